// Round 4
// baseline (157.354 us; speedup 1.0000x reference)
//
#include <hip/hip_runtime.h>
#include <stdint.h>

// ---- problem constants ----
constexpr int NB   = 4;      // batch
constexpr int CIN  = 3;
constexpr int HIN  = 256;
constexpr int COUT = 256;
constexpr int HF   = 128;              // feature H=W after stride-2 conv
constexpr int NF   = HF * HF;          // 16384
constexpr int KADM = 16;
constexpr int KK   = KADM * KADM;      // 256 descriptors
constexpr int HID  = 128;              // MLP hidden

typedef unsigned short ushort_t;
typedef __attribute__((ext_vector_type(8))) _Float16 f16x8;
typedef __attribute__((ext_vector_type(4))) float    f32x4;

__device__ inline unsigned long long shfl_xor_u64(unsigned long long v, int m) {
    unsigned lo = __shfl_xor((unsigned)v, m, 64);
    unsigned hi = __shfl_xor((unsigned)(v >> 32), m, 64);
    return ((unsigned long long)hi << 32) | lo;
}
__device__ inline unsigned long long shfl_down_u64(unsigned long long v, int off) {
    unsigned lo = __shfl_down((unsigned)v, off, 64);
    unsigned hi = __shfl_down((unsigned)(v >> 32), off, 64);
    return ((unsigned long long)hi << 32) | lo;
}
__device__ inline unsigned long long u64min(unsigned long long a, unsigned long long b) {
    return a < b ? a : b;
}

// =====================================================================
// Conv 3->256 k3 s2 p1 + ReLU.  Weights via wave-uniform (SGPR) loads.
// A-images: emit only resp = sum_c. B-images: fB fp32 [c][n] + normB.
// =====================================================================
__global__ __launch_bounds__(256) void conv_kernel(
        const float* __restrict__ xA, const float* __restrict__ xB,
        const float* __restrict__ W,  const float* __restrict__ bias,
        float* __restrict__ fB, float* __restrict__ resp, float* __restrict__ normB)
{
    __shared__ float pS[CIN][9][129];

    int blk  = blockIdx.x;           // 0..511
    int img  = blk >> 6;             // 0..7 (0..3 = A, 4..7 = B)
    int tile = blk & 63;
    int ty0  = (tile >> 1) * 4;
    int tx0  = (tile & 1) * 64;
    int tid  = threadIdx.x;
    bool isA = (img < 4);

    const float* x = isA ? (xA + (size_t)img * CIN * HIN * HIN)
                         : (xB + (size_t)(img - 4) * CIN * HIN * HIN);

    for (int i = tid; i < CIN * 9 * 129; i += 256) {
        int ci  = i / (9 * 129);
        int rem = i % (9 * 129);
        int r = rem / 129, c = rem % 129;
        int gr = ty0 * 2 - 1 + r, gc = tx0 * 2 - 1 + c;
        float v = 0.f;
        if (gr >= 0 && gr < HIN && gc >= 0 && gc < HIN)
            v = x[(size_t)ci * HIN * HIN + (size_t)gr * HIN + gc];
        pS[ci][r][c] = v;
    }
    __syncthreads();

    int tx = tid & 63, ty = tid >> 6;
    float p[27];
    #pragma unroll
    for (int ci = 0; ci < CIN; ++ci)
        #pragma unroll
        for (int kh = 0; kh < 3; ++kh)
            #pragma unroll
            for (int kw = 0; kw < 3; ++kw)
                p[ci * 9 + kh * 3 + kw] = pS[ci][ty * 2 + kh][tx * 2 + kw];

    int oh = ty0 + ty, ow = tx0 + tx;
    int imgL = img & 3;
    size_t obase = (size_t)imgL * COUT * NF + (size_t)oh * HF + ow;

    float sum = 0.f, sumsq = 0.f;
    #pragma unroll 4
    for (int co = 0; co < COUT; ++co) {
        float v = bias[co];                     // uniform -> SGPR load
        const float* w = &W[co * 27];           // uniform -> SGPR loads
        #pragma unroll
        for (int q = 0; q < 27; ++q)
            v = fmaf(p[q], w[q], v);
        v = fmaxf(v, 0.f);
        if (!isA) fB[obase + (size_t)co * NF] = v;
        sum += v;
        sumsq = fmaf(v, v, sumsq);
    }
    if (isA) resp [(size_t)imgL * NF + (size_t)oh * HF + ow] = sum;
    else     normB[(size_t)imgL * NF + (size_t)oh * HF + ow] = sumsq;
}

// =====================================================================
// Fused select: pool argmax (wave 0) + descriptor conv-recompute.
// Block per (b,k): threads 0..63 do 8x8 argmax on resp; then all 256
// threads recompute conv at the chosen pixel (t = channel), emit desc
// f16 hi/lo + normA.
// =====================================================================
__global__ __launch_bounds__(256) void select_kernel(
        const float* __restrict__ resp,
        const float* __restrict__ xA, const float* __restrict__ W,
        const float* __restrict__ bias,
        int* __restrict__ idxA,
        ushort_t* __restrict__ desc_h, ushort_t* __restrict__ desc_l,
        float* __restrict__ normA)
{
    __shared__ float patch[27];
    __shared__ float red[4];
    __shared__ int   sidx;

    int bk = blockIdx.x;              // b*KK + k
    int b = bk >> 8, kIdx = bk & 255;
    int t = threadIdx.x;

    // ---- pool argmax on wave 0 ----
    if (t < 64) {
        int kr = kIdx >> 4, kc = kIdx & 15;
        int lr = t >> 3, lc = t & 7;
        int row = kr * 8 + lr, col = kc * 8 + lc;
        float bv = resp[(size_t)b * NF + (size_t)row * HF + col];
        int best = t;
        for (int off = 32; off > 0; off >>= 1) {
            float ov = __shfl_down(bv, off, 64);
            int   oi = __shfl_down(best, off, 64);
            if (ov > bv || (ov == bv && oi < best)) { bv = ov; best = oi; }
        }
        if (t == 0) {
            int r = kr * 8 + (best >> 3), c = kc * 8 + (best & 7);
            int idx = r * HF + c;
            idxA[bk] = idx;
            sidx = idx;
        }
    }
    __syncthreads();
    int idx = sidx;
    int oh = idx >> 7, ow = idx & 127;

    if (t < 27) {
        int ci = t / 9, kh = (t % 9) / 3, kw = t % 3;
        int ir = oh * 2 - 1 + kh, ic = ow * 2 - 1 + kw;
        float v = 0.f;
        if (ir >= 0 && ir < HIN && ic >= 0 && ic < HIN)
            v = xA[((size_t)b * CIN + ci) * HIN * HIN + (size_t)ir * HIN + ic];
        patch[t] = v;
    }
    __syncthreads();

    float v = bias[t];
    const float* w = &W[t * 27];
    #pragma unroll
    for (int q = 0; q < 27; ++q) v = fmaf(patch[q], w[q], v);
    v = fmaxf(v, 0.f);

    _Float16 h = (_Float16)v;
    _Float16 l = (_Float16)(v - (float)h);
    desc_h[(size_t)bk * COUT + t] = __builtin_bit_cast(ushort_t, h);
    desc_l[(size_t)bk * COUT + t] = __builtin_bit_cast(ushort_t, l);

    float s = v * v;
    for (int off = 32; off > 0; off >>= 1) s += __shfl_down(s, off, 64);
    if ((t & 63) == 0) red[t >> 6] = s;
    __syncthreads();
    if (t == 0) normA[bk] = red[0] + red[1] + red[2] + red[3];
}

// =====================================================================
// MFMA kNN: per block (nb,b): 64 pixels x 256 k, K=c chunked by 32.
// fp16x2 split: dot = fh*dh + fl*dh + fh*dl.
// =====================================================================
__global__ __launch_bounds__(256) void knn_kernel(
        const float* __restrict__ fB,
        const ushort_t* __restrict__ desc_h, const ushort_t* __restrict__ desc_l,
        const float* __restrict__ normA, const float* __restrict__ normB,
        unsigned long long* __restrict__ scratch)
{
    __shared__ ushort_t Bs[2][64][40];   // [hi/lo][n][c-chunk], 80B row stride
    __shared__ float nAS[KK];
    __shared__ float nBS[64];

    int nb = blockIdx.x;      // 0..255
    int b  = blockIdx.y;      // 0..3
    int tid = threadIdx.x;
    int lane = tid & 63, w = tid >> 6;
    int n0 = nb * 64;

    if (tid < 64) nBS[tid] = normB[(size_t)b * NF + n0 + tid];
    nAS[tid] = normA[b * KK + tid];

    const float* fBp = fB + (size_t)b * COUT * NF;
    const ushort_t* dh = desc_h + (size_t)b * KK * COUT;
    const ushort_t* dl = desc_l + (size_t)b * KK * COUT;

    f32x4 acc[4][4];
    #pragma unroll
    for (int i = 0; i < 4; ++i)
        #pragma unroll
        for (int j = 0; j < 4; ++j) acc[i][j] = (f32x4)0.f;

    int sn  = tid >> 2;       // staging pixel row 0..63
    int cp0 = tid & 3;        // staging c-pair base

    int la = lane & 15, lg = lane >> 4;   // fragment indices
    int kw0 = w * 64;

    for (int cc = 0; cc < COUT; cc += 32) {
        __syncthreads();
        #pragma unroll
        for (int it = 0; it < 4; ++it) {
            int c = (cp0 + it * 4) * 2;
            float v0 = fBp[(size_t)(cc + c)     * NF + n0 + sn];
            float v1 = fBp[(size_t)(cc + c + 1) * NF + n0 + sn];
            _Float16 h0 = (_Float16)v0, h1 = (_Float16)v1;
            _Float16 l0 = (_Float16)(v0 - (float)h0), l1 = (_Float16)(v1 - (float)h1);
            unsigned uh = (unsigned)__builtin_bit_cast(ushort_t, h0)
                        | ((unsigned)__builtin_bit_cast(ushort_t, h1) << 16);
            unsigned ul = (unsigned)__builtin_bit_cast(ushort_t, l0)
                        | ((unsigned)__builtin_bit_cast(ushort_t, l1) << 16);
            *(unsigned*)&Bs[0][sn][c] = uh;
            *(unsigned*)&Bs[1][sn][c] = ul;
        }
        __syncthreads();

        f16x8 bfrag[4], afrag[4];
        // pass 1: fh * dh
        #pragma unroll
        for (int j = 0; j < 4; ++j)
            bfrag[j] = *(const f16x8*)&dh[(size_t)(kw0 + j * 16 + la) * COUT + cc + lg * 8];
        #pragma unroll
        for (int i = 0; i < 4; ++i)
            afrag[i] = *(const f16x8*)&Bs[0][i * 16 + la][lg * 8];
        #pragma unroll
        for (int i = 0; i < 4; ++i)
            #pragma unroll
            for (int j = 0; j < 4; ++j)
                acc[i][j] = __builtin_amdgcn_mfma_f32_16x16x32_f16(afrag[i], bfrag[j], acc[i][j], 0, 0, 0);
        // pass 2: fl * dh
        #pragma unroll
        for (int i = 0; i < 4; ++i)
            afrag[i] = *(const f16x8*)&Bs[1][i * 16 + la][lg * 8];
        #pragma unroll
        for (int i = 0; i < 4; ++i)
            #pragma unroll
            for (int j = 0; j < 4; ++j)
                acc[i][j] = __builtin_amdgcn_mfma_f32_16x16x32_f16(afrag[i], bfrag[j], acc[i][j], 0, 0, 0);
        // pass 3: fh * dl
        #pragma unroll
        for (int j = 0; j < 4; ++j)
            bfrag[j] = *(const f16x8*)&dl[(size_t)(kw0 + j * 16 + la) * COUT + cc + lg * 8];
        #pragma unroll
        for (int i = 0; i < 4; ++i)
            afrag[i] = *(const f16x8*)&Bs[0][i * 16 + la][lg * 8];
        #pragma unroll
        for (int i = 0; i < 4; ++i)
            #pragma unroll
            for (int j = 0; j < 4; ++j)
                acc[i][j] = __builtin_amdgcn_mfma_f32_16x16x32_f16(afrag[i], bfrag[j], acc[i][j], 0, 0, 0);
    }

    // ---- epilogue: dist + per-k argmin ----
    float nBv[4][4];
    #pragma unroll
    for (int i = 0; i < 4; ++i) {
        f32x4 t4 = *(const f32x4*)&nBS[i * 16 + lg * 4];
        nBv[i][0] = t4[0]; nBv[i][1] = t4[1]; nBv[i][2] = t4[2]; nBv[i][3] = t4[3];
    }
    #pragma unroll
    for (int j = 0; j < 4; ++j) {
        int kl = kw0 + j * 16 + la;
        float nAv = nAS[kl];
        unsigned long long best = ~0ull;
        #pragma unroll
        for (int i = 0; i < 4; ++i)
            #pragma unroll
            for (int r = 0; r < 4; ++r) {
                int n = n0 + i * 16 + lg * 4 + r;
                float d = fmaf(-2.f, acc[i][j][r], nAv) + nBv[i][r];
                unsigned u = __float_as_uint(d);
                u = (u & 0x80000000u) ? ~u : (u | 0x80000000u);
                unsigned long long key = ((unsigned long long)u << 32) | (unsigned)n;
                best = u64min(best, key);
            }
        best = u64min(best, shfl_xor_u64(best, 16));
        best = u64min(best, shfl_xor_u64(best, 32));
        if (lg == 0)
            scratch[(size_t)(b * KK + kl) * 256 + nb] = best;
    }
}

// =====================================================================
// Final argmin reduce over the 256 nb-blocks -> minN[b*KK + k]
// =====================================================================
__global__ __launch_bounds__(64) void reduce_kernel(
        const unsigned long long* __restrict__ scratch, int* __restrict__ minN)
{
    int bk = blockIdx.x;              // b*KK + k
    int t = threadIdx.x;
    const unsigned long long* s = scratch + (size_t)bk * 256;
    unsigned long long best = s[t];
    best = u64min(best, s[t + 64]);
    best = u64min(best, s[t + 128]);
    best = u64min(best, s[t + 192]);
    for (int off = 32; off > 0; off >>= 1)
        best = u64min(best, shfl_down_u64(best, off));
    if (t == 0) minN[bk] = (int)(best & 0xffffffffULL);
}

// =====================================================================
// Two tiny MLPs: x(256) -> 128 relu -> 1. block per (b, which), 128 threads.
// =====================================================================
__global__ __launch_bounds__(128) void mlp_kernel(
        const int* __restrict__ idxA, const int* __restrict__ minN,
        const float* __restrict__ W1r, const float* __restrict__ b1r,
        const float* __restrict__ W2r, const float* __restrict__ b2r,
        const float* __restrict__ W1c, const float* __restrict__ b1c,
        const float* __restrict__ W2c, const float* __restrict__ b2c,
        float* __restrict__ out)
{
    __shared__ float xS[KK];
    __shared__ float red[2];
    int blk = blockIdx.x;            // b*2 + which
    int b = blk >> 1, which = blk & 1;
    int t = threadIdx.x;             // 0..127

    for (int k = t; k < KK; k += 128) {
        int ia = idxA[b * KK + k];
        int nn = minN[b * KK + k];
        int rowA = ia >> 7, colA = ia & 127;
        int rowB = nn >> 7, colB = nn & 127;
        xS[k] = (which == 0) ? (float)(rowB - rowA) : (float)(colA - colB);
    }
    __syncthreads();

    const float* W1 = which ? W1c : W1r;
    const float* b1 = which ? b1c : b1r;
    const float* W2 = which ? W2c : W2r;
    const float* b2 = which ? b2c : b2r;

    float h = b1[t];
    for (int k = 0; k < KK; ++k) h = fmaf(xS[k], W1[k * HID + t], h);
    h = fmaxf(h, 0.f);
    float pv = h * W2[t];
    for (int off = 32; off > 0; off >>= 1) pv += __shfl_down(pv, off, 64);
    if ((t & 63) == 0) red[t >> 6] = pv;
    __syncthreads();
    if (t == 0) out[b * 2 + which] = red[0] + red[1] + b2[0];
}

// =====================================================================
extern "C" void kernel_launch(void* const* d_in, const int* in_sizes, int n_in,
                              void* d_out, int out_size, void* d_ws, size_t ws_size,
                              hipStream_t stream)
{
    const float* xA  = (const float*)d_in[0];
    const float* xB  = (const float*)d_in[1];
    const float* Wc  = (const float*)d_in[2];
    const float* bc  = (const float*)d_in[3];
    const float* W1r = (const float*)d_in[4];
    const float* b1r = (const float*)d_in[5];
    const float* W2r = (const float*)d_in[6];
    const float* b2r = (const float*)d_in[7];
    const float* W1c = (const float*)d_in[8];
    const float* b1c = (const float*)d_in[9];
    const float* W2c = (const float*)d_in[10];
    const float* b2c = (const float*)d_in[11];
    float* out = (float*)d_out;

    char* ws = (char*)d_ws;
    unsigned long long* scratch = (unsigned long long*)ws; ws += (size_t)NB * KK * 256 * 8;
    int*   idxA   = (int*)ws;      ws += (size_t)NB * KK * 4;
    int*   minN   = (int*)ws;      ws += (size_t)NB * KK * 4;
    float* normA  = (float*)ws;    ws += (size_t)NB * KK * 4;
    float* resp   = (float*)ws;    ws += (size_t)NB * NF * 4;
    float* normB  = (float*)ws;    ws += (size_t)NB * NF * 4;
    ushort_t* desc_h = (ushort_t*)ws; ws += (size_t)NB * KK * COUT * 2;
    ushort_t* desc_l = (ushort_t*)ws; ws += (size_t)NB * KK * COUT * 2;
    float* fB     = (float*)ws;    ws += (size_t)NB * COUT * NF * 4;

    conv_kernel  <<<512, 256, 0, stream>>>(xA, xB, Wc, bc, fB, resp, normB);
    select_kernel<<<NB * KK, 256, 0, stream>>>(resp, xA, Wc, bc, idxA, desc_h, desc_l, normA);
    knn_kernel   <<<dim3(256, NB), 256, 0, stream>>>(fB, desc_h, desc_l, normA, normB, scratch);
    reduce_kernel<<<NB * KK, 64, 0, stream>>>(scratch, minN);
    mlp_kernel   <<<8, 128, 0, stream>>>(idxA, minN,
                                         W1r, b1r, W2r, b2r,
                                         W1c, b1c, W2c, b2c, out);
}

// Round 5
// 102.759 us; speedup vs baseline: 1.5313x; 1.5313x over previous
//
#include <hip/hip_runtime.h>
#include <stdint.h>

// ---- problem constants ----
constexpr int NB   = 4;      // batch
constexpr int CIN  = 3;
constexpr int HIN  = 256;
constexpr int COUT = 256;
constexpr int HF   = 128;              // feature H=W after stride-2 conv
constexpr int NF   = HF * HF;          // 16384
constexpr int KADM = 16;
constexpr int KK   = KADM * KADM;      // 256 descriptors
constexpr int HID  = 128;              // MLP hidden

typedef unsigned short ushort_t;
typedef __attribute__((ext_vector_type(8))) _Float16 f16x8;
typedef __attribute__((ext_vector_type(4))) float    f32x4;

__device__ inline unsigned long long shfl_xor_u64(unsigned long long v, int m) {
    unsigned lo = __shfl_xor((unsigned)v, m, 64);
    unsigned hi = __shfl_xor((unsigned)(v >> 32), m, 64);
    return ((unsigned long long)hi << 32) | lo;
}
__device__ inline unsigned long long shfl_down_u64(unsigned long long v, int off) {
    unsigned lo = __shfl_down((unsigned)v, off, 64);
    unsigned hi = __shfl_down((unsigned)(v >> 32), off, 64);
    return ((unsigned long long)hi << 32) | lo;
}
__device__ inline unsigned long long u64min(unsigned long long a, unsigned long long b) {
    return a < b ? a : b;
}
__device__ inline ushort_t f16bits(_Float16 h) { return __builtin_bit_cast(ushort_t, h); }

// =====================================================================
// Prep: split conv weights into f16 hi/lo, K padded 27->32.
// =====================================================================
__global__ __launch_bounds__(256) void prep_kernel(
        const float* __restrict__ W, ushort_t* __restrict__ Wh, ushort_t* __restrict__ Wl)
{
    int t = threadIdx.x;            // co
    #pragma unroll
    for (int q = 0; q < 32; ++q) {
        float v = (q < 27) ? W[t * 27 + q] : 0.f;
        _Float16 h = (_Float16)v;
        _Float16 l = (_Float16)(v - (float)h);
        Wh[t * 32 + q] = f16bits(h);
        Wl[t * 32 + q] = f16bits(l);
    }
}

// =====================================================================
// Conv as MFMA im2col GEMM: [64 pixels x 32(K)] x [32 x 256 channels].
// f16x2 split, 3 passes: xh*wh + xl*wh + xh*wl.
// A images: emit resp = sum_c relu(v). B images: fBhl packed u32 + normB.
// Block: 256 thr = 4 waves; wave w owns channels w*64..w*64+63.
// Grid: img(8) x row(128) x xtile(2).
// =====================================================================
__global__ __launch_bounds__(256) void conv_kernel(
        const float* __restrict__ xA, const float* __restrict__ xB,
        const ushort_t* __restrict__ Wh, const ushort_t* __restrict__ Wl,
        const float* __restrict__ bias,
        unsigned* __restrict__ fBhl, float* __restrict__ resp, float* __restrict__ normB)
{
    __shared__ float    pS[CIN][3][132];    // input rows
    __shared__ ushort_t Ah[64][40];         // im2col hi, 80B row stride
    __shared__ ushort_t Al[64][40];         // im2col lo
    __shared__ float    bS[COUT];
    __shared__ float    redS[4][64];

    int blk = blockIdx.x;            // 0..2047
    int img = blk >> 8;              // 0..7
    int rem = blk & 255;
    int oh  = rem >> 1;
    int ow0 = (rem & 1) << 6;
    bool isA = (img < 4);
    int b = img & 3;
    const float* x = isA ? (xA + (size_t)b * CIN * HIN * HIN)
                         : (xB + (size_t)b * CIN * HIN * HIN);
    int tid = threadIdx.x;

    bS[tid] = bias[tid];

    // stage 9 input rows of 129
    for (int i = tid; i < CIN * 3 * 129; i += 256) {
        int ci = i / (3 * 129);
        int r2 = i % (3 * 129);
        int kh = r2 / 129, c = r2 % 129;
        int gr = 2 * oh - 1 + kh, gc = 2 * ow0 - 1 + c;
        float v = 0.f;
        if (gr >= 0 && gr < HIN && gc >= 0 && gc < HIN)
            v = x[(size_t)ci * HIN * HIN + (size_t)gr * HIN + gc];
        pS[ci][kh][c] = v;
    }
    __syncthreads();

    // im2col into Ah/Al: thread -> pixel n = tid>>2, q-group qg = tid&3
    {
        int n = tid >> 2, qg = tid & 3;
        unsigned uh[4], ul[4];
        #pragma unroll
        for (int e2 = 0; e2 < 4; ++e2) {
            ushort_t hh[2], ll[2];
            #pragma unroll
            for (int s = 0; s < 2; ++s) {
                int q = qg * 8 + e2 * 2 + s;
                float v = 0.f;
                if (q < 27) {
                    int ci = q / 9, r = (q % 9) / 3, kw = q % 3;
                    v = pS[ci][r][2 * n + kw];
                }
                _Float16 h = (_Float16)v;
                _Float16 l = (_Float16)(v - (float)h);
                hh[s] = f16bits(h); ll[s] = f16bits(l);
            }
            uh[e2] = (unsigned)hh[0] | ((unsigned)hh[1] << 16);
            ul[e2] = (unsigned)ll[0] | ((unsigned)ll[1] << 16);
        }
        *(uint4*)&Ah[n][qg * 8] = *(uint4*)uh;
        *(uint4*)&Al[n][qg * 8] = *(uint4*)ul;
    }
    __syncthreads();

    int lane = tid & 63, w = tid >> 6;
    int la = lane & 15, lg = lane >> 4;
    int wbase = w * 64;

    f16x8 ah[4], al[4], bh[4], bl[4];
    #pragma unroll
    for (int i = 0; i < 4; ++i) {
        ah[i] = *(const f16x8*)&Ah[i * 16 + la][lg * 8];
        al[i] = *(const f16x8*)&Al[i * 16 + la][lg * 8];
    }
    #pragma unroll
    for (int j = 0; j < 4; ++j) {
        int co = wbase + j * 16 + la;
        bh[j] = *(const f16x8*)&Wh[co * 32 + lg * 8];
        bl[j] = *(const f16x8*)&Wl[co * 32 + lg * 8];
    }

    f32x4 acc[4][4];
    #pragma unroll
    for (int i = 0; i < 4; ++i)
        #pragma unroll
        for (int j = 0; j < 4; ++j) acc[i][j] = (f32x4)0.f;

    #pragma unroll
    for (int i = 0; i < 4; ++i)
        #pragma unroll
        for (int j = 0; j < 4; ++j) {
            acc[i][j] = __builtin_amdgcn_mfma_f32_16x16x32_f16(ah[i], bh[j], acc[i][j], 0, 0, 0);
            acc[i][j] = __builtin_amdgcn_mfma_f32_16x16x32_f16(al[i], bh[j], acc[i][j], 0, 0, 0);
            acc[i][j] = __builtin_amdgcn_mfma_f32_16x16x32_f16(ah[i], bl[j], acc[i][j], 0, 0, 0);
        }

    // epilogue: bias + relu; B: pack+store fBhl; both: per-pixel channel sum
    float bj[4];
    #pragma unroll
    for (int j = 0; j < 4; ++j) bj[j] = bS[wbase + j * 16 + la];

    int pixbase = oh * HF + ow0;                 // flat pixel of this row tile
    float s[4][4];                               // [i][r] sum over j of f(v)
    #pragma unroll
    for (int i = 0; i < 4; ++i)
        #pragma unroll
        for (int r = 0; r < 4; ++r) s[i][r] = 0.f;

    #pragma unroll
    for (int i = 0; i < 4; ++i) {
        #pragma unroll
        for (int j = 0; j < 4; ++j) {
            unsigned pk[4];
            #pragma unroll
            for (int r = 0; r < 4; ++r) {
                float v = fmaxf(acc[i][j][r] + bj[j], 0.f);
                if (!isA) {
                    _Float16 h = (_Float16)v;
                    _Float16 l = (_Float16)(v - (float)h);
                    pk[r] = (unsigned)f16bits(h) | ((unsigned)f16bits(l) << 16);
                }
                s[i][r] += isA ? v : v * v;
            }
            if (!isA) {
                int co = wbase + j * 16 + la;
                size_t addr = (size_t)(b * COUT + co) * NF + pixbase + i * 16 + lg * 4;
                *(uint4*)&fBhl[addr] = *(uint4*)pk;
            }
        }
    }
    // reduce s over la (lane bits 0..3)
    #pragma unroll
    for (int i = 0; i < 4; ++i)
        #pragma unroll
        for (int r = 0; r < 4; ++r) {
            float v = s[i][r];
            v += __shfl_xor(v, 1, 64);
            v += __shfl_xor(v, 2, 64);
            v += __shfl_xor(v, 4, 64);
            v += __shfl_xor(v, 8, 64);
            s[i][r] = v;
        }
    if (la == 0) {
        #pragma unroll
        for (int i = 0; i < 4; ++i)
            #pragma unroll
            for (int r = 0; r < 4; ++r)
                redS[w][i * 16 + lg * 4 + r] = s[i][r];
    }
    __syncthreads();
    if (tid < 64) {
        float tot = redS[0][tid] + redS[1][tid] + redS[2][tid] + redS[3][tid];
        size_t addr = (size_t)b * NF + pixbase + tid;
        if (isA) resp[addr] = tot;
        else     normB[addr] = tot;
    }
}

// =====================================================================
// Fused select: pool argmax (wave 0) + descriptor conv-recompute (fp32 exact).
// =====================================================================
__global__ __launch_bounds__(256) void select_kernel(
        const float* __restrict__ resp,
        const float* __restrict__ xA, const float* __restrict__ W,
        const float* __restrict__ bias,
        int* __restrict__ idxA,
        ushort_t* __restrict__ desc_h, ushort_t* __restrict__ desc_l,
        float* __restrict__ normA)
{
    __shared__ float patch[27];
    __shared__ float red[4];
    __shared__ int   sidx;

    int bk = blockIdx.x;              // b*KK + k
    int b = bk >> 8, kIdx = bk & 255;
    int t = threadIdx.x;

    if (t < 64) {
        int kr = kIdx >> 4, kc = kIdx & 15;
        int lr = t >> 3, lc = t & 7;
        int row = kr * 8 + lr, col = kc * 8 + lc;
        float bv = resp[(size_t)b * NF + (size_t)row * HF + col];
        int best = t;
        for (int off = 32; off > 0; off >>= 1) {
            float ov = __shfl_down(bv, off, 64);
            int   oi = __shfl_down(best, off, 64);
            if (ov > bv || (ov == bv && oi < best)) { bv = ov; best = oi; }
        }
        if (t == 0) {
            int r = kr * 8 + (best >> 3), c = kc * 8 + (best & 7);
            int idx = r * HF + c;
            idxA[bk] = idx;
            sidx = idx;
        }
    }
    __syncthreads();
    int idx = sidx;
    int oh = idx >> 7, ow = idx & 127;

    if (t < 27) {
        int ci = t / 9, kh = (t % 9) / 3, kw = t % 3;
        int ir = oh * 2 - 1 + kh, ic = ow * 2 - 1 + kw;
        float v = 0.f;
        if (ir >= 0 && ir < HIN && ic >= 0 && ic < HIN)
            v = xA[((size_t)b * CIN + ci) * HIN * HIN + (size_t)ir * HIN + ic];
        patch[t] = v;
    }
    __syncthreads();

    float v = bias[t];
    const float* w = &W[t * 27];
    #pragma unroll
    for (int q = 0; q < 27; ++q) v = fmaf(patch[q], w[q], v);
    v = fmaxf(v, 0.f);

    _Float16 h = (_Float16)v;
    _Float16 l = (_Float16)(v - (float)h);
    desc_h[(size_t)bk * COUT + t] = f16bits(h);
    desc_l[(size_t)bk * COUT + t] = f16bits(l);

    float s = v * v;
    for (int off = 32; off > 0; off >>= 1) s += __shfl_down(s, off, 64);
    if ((t & 63) == 0) red[t >> 6] = s;
    __syncthreads();
    if (t == 0) normA[bk] = red[0] + red[1] + red[2] + red[3];
}

// =====================================================================
// MFMA kNN: per block (nb,b): 64 pixels x 256 k, K=c chunked by 32.
// fp16x2 split: dot = fh*dh + fl*dh + fh*dl.  fB read as packed h/l u32.
// =====================================================================
__global__ __launch_bounds__(256) void knn_kernel(
        const unsigned* __restrict__ fBhl,
        const ushort_t* __restrict__ desc_h, const ushort_t* __restrict__ desc_l,
        const float* __restrict__ normA, const float* __restrict__ normB,
        unsigned long long* __restrict__ scratch)
{
    __shared__ ushort_t Bs[2][64][40];   // [hi/lo][n][c-chunk], 80B row stride
    __shared__ float nAS[KK];
    __shared__ float nBS[64];

    int nb = blockIdx.x;      // 0..255
    int b  = blockIdx.y;      // 0..3
    int tid = threadIdx.x;
    int lane = tid & 63, w = tid >> 6;
    int n0 = nb * 64;

    if (tid < 64) nBS[tid] = normB[(size_t)b * NF + n0 + tid];
    nAS[tid] = normA[b * KK + tid];

    const unsigned* fBp = fBhl + (size_t)b * COUT * NF;
    const ushort_t* dh = desc_h + (size_t)b * KK * COUT;
    const ushort_t* dl = desc_l + (size_t)b * KK * COUT;

    f32x4 acc[4][4];
    #pragma unroll
    for (int i = 0; i < 4; ++i)
        #pragma unroll
        for (int j = 0; j < 4; ++j) acc[i][j] = (f32x4)0.f;

    int sn  = tid >> 2;       // staging pixel row 0..63
    int cp0 = tid & 3;        // staging c-pair base

    int la = lane & 15, lg = lane >> 4;   // fragment indices
    int kw0 = w * 64;

    for (int cc = 0; cc < COUT; cc += 32) {
        __syncthreads();
        #pragma unroll
        for (int it = 0; it < 4; ++it) {
            int c = (cp0 + it * 4) * 2;
            unsigned u0 = fBp[(size_t)(cc + c)     * NF + n0 + sn];
            unsigned u1 = fBp[(size_t)(cc + c + 1) * NF + n0 + sn];
            unsigned uh = (u0 & 0xffffu) | (u1 << 16);
            unsigned ul = (u0 >> 16) | (u1 & 0xffff0000u);
            *(unsigned*)&Bs[0][sn][c] = uh;
            *(unsigned*)&Bs[1][sn][c] = ul;
        }
        __syncthreads();

        f16x8 bfrag[4], afrag[4];
        // pass 1: fh * dh
        #pragma unroll
        for (int j = 0; j < 4; ++j)
            bfrag[j] = *(const f16x8*)&dh[(size_t)(kw0 + j * 16 + la) * COUT + cc + lg * 8];
        #pragma unroll
        for (int i = 0; i < 4; ++i)
            afrag[i] = *(const f16x8*)&Bs[0][i * 16 + la][lg * 8];
        #pragma unroll
        for (int i = 0; i < 4; ++i)
            #pragma unroll
            for (int j = 0; j < 4; ++j)
                acc[i][j] = __builtin_amdgcn_mfma_f32_16x16x32_f16(afrag[i], bfrag[j], acc[i][j], 0, 0, 0);
        // pass 2: fl * dh
        #pragma unroll
        for (int i = 0; i < 4; ++i)
            afrag[i] = *(const f16x8*)&Bs[1][i * 16 + la][lg * 8];
        #pragma unroll
        for (int i = 0; i < 4; ++i)
            #pragma unroll
            for (int j = 0; j < 4; ++j)
                acc[i][j] = __builtin_amdgcn_mfma_f32_16x16x32_f16(afrag[i], bfrag[j], acc[i][j], 0, 0, 0);
        // pass 3: fh * dl
        #pragma unroll
        for (int j = 0; j < 4; ++j)
            bfrag[j] = *(const f16x8*)&dl[(size_t)(kw0 + j * 16 + la) * COUT + cc + lg * 8];
        #pragma unroll
        for (int i = 0; i < 4; ++i)
            afrag[i] = *(const f16x8*)&Bs[0][i * 16 + la][lg * 8];
        #pragma unroll
        for (int i = 0; i < 4; ++i)
            #pragma unroll
            for (int j = 0; j < 4; ++j)
                acc[i][j] = __builtin_amdgcn_mfma_f32_16x16x32_f16(afrag[i], bfrag[j], acc[i][j], 0, 0, 0);
    }

    // ---- epilogue: dist + per-k argmin ----
    float nBv[4][4];
    #pragma unroll
    for (int i = 0; i < 4; ++i) {
        f32x4 t4 = *(const f32x4*)&nBS[i * 16 + lg * 4];
        nBv[i][0] = t4[0]; nBv[i][1] = t4[1]; nBv[i][2] = t4[2]; nBv[i][3] = t4[3];
    }
    #pragma unroll
    for (int j = 0; j < 4; ++j) {
        int kl = kw0 + j * 16 + la;
        float nAv = nAS[kl];
        unsigned long long best = ~0ull;
        #pragma unroll
        for (int i = 0; i < 4; ++i)
            #pragma unroll
            for (int r = 0; r < 4; ++r) {
                int n = n0 + i * 16 + lg * 4 + r;
                float d = fmaf(-2.f, acc[i][j][r], nAv) + nBv[i][r];
                unsigned u = __float_as_uint(d);
                u = (u & 0x80000000u) ? ~u : (u | 0x80000000u);
                unsigned long long key = ((unsigned long long)u << 32) | (unsigned)n;
                best = u64min(best, key);
            }
        best = u64min(best, shfl_xor_u64(best, 16));
        best = u64min(best, shfl_xor_u64(best, 32));
        if (lg == 0)
            scratch[(size_t)(b * KK + kl) * 256 + nb] = best;
    }
}

// =====================================================================
// Final argmin reduce over the 256 nb-blocks -> minN[b*KK + k]
// =====================================================================
__global__ __launch_bounds__(64) void reduce_kernel(
        const unsigned long long* __restrict__ scratch, int* __restrict__ minN)
{
    int bk = blockIdx.x;              // b*KK + k
    int t = threadIdx.x;
    const unsigned long long* s = scratch + (size_t)bk * 256;
    unsigned long long best = s[t];
    best = u64min(best, s[t + 64]);
    best = u64min(best, s[t + 128]);
    best = u64min(best, s[t + 192]);
    for (int off = 32; off > 0; off >>= 1)
        best = u64min(best, shfl_down_u64(best, off));
    if (t == 0) minN[bk] = (int)(best & 0xffffffffULL);
}

// =====================================================================
// Two tiny MLPs: x(256) -> 128 relu -> 1. block per (b, which), 128 threads.
// =====================================================================
__global__ __launch_bounds__(128) void mlp_kernel(
        const int* __restrict__ idxA, const int* __restrict__ minN,
        const float* __restrict__ W1r, const float* __restrict__ b1r,
        const float* __restrict__ W2r, const float* __restrict__ b2r,
        const float* __restrict__ W1c, const float* __restrict__ b1c,
        const float* __restrict__ W2c, const float* __restrict__ b2c,
        float* __restrict__ out)
{
    __shared__ float xS[KK];
    __shared__ float red[2];
    int blk = blockIdx.x;            // b*2 + which
    int b = blk >> 1, which = blk & 1;
    int t = threadIdx.x;             // 0..127

    for (int k = t; k < KK; k += 128) {
        int ia = idxA[b * KK + k];
        int nn = minN[b * KK + k];
        int rowA = ia >> 7, colA = ia & 127;
        int rowB = nn >> 7, colB = nn & 127;
        xS[k] = (which == 0) ? (float)(rowB - rowA) : (float)(colA - colB);
    }
    __syncthreads();

    const float* W1 = which ? W1c : W1r;
    const float* b1 = which ? b1c : b1r;
    const float* W2 = which ? W2c : W2r;
    const float* b2 = which ? b2c : b2r;

    float h = b1[t];
    for (int k = 0; k < KK; ++k) h = fmaf(xS[k], W1[k * HID + t], h);
    h = fmaxf(h, 0.f);
    float pv = h * W2[t];
    for (int off = 32; off > 0; off >>= 1) pv += __shfl_down(pv, off, 64);
    if ((t & 63) == 0) red[t >> 6] = pv;
    __syncthreads();
    if (t == 0) out[b * 2 + which] = red[0] + red[1] + b2[0];
}

// =====================================================================
extern "C" void kernel_launch(void* const* d_in, const int* in_sizes, int n_in,
                              void* d_out, int out_size, void* d_ws, size_t ws_size,
                              hipStream_t stream)
{
    const float* xA  = (const float*)d_in[0];
    const float* xB  = (const float*)d_in[1];
    const float* Wc  = (const float*)d_in[2];
    const float* bc  = (const float*)d_in[3];
    const float* W1r = (const float*)d_in[4];
    const float* b1r = (const float*)d_in[5];
    const float* W2r = (const float*)d_in[6];
    const float* b2r = (const float*)d_in[7];
    const float* W1c = (const float*)d_in[8];
    const float* b1c = (const float*)d_in[9];
    const float* W2c = (const float*)d_in[10];
    const float* b2c = (const float*)d_in[11];
    float* out = (float*)d_out;

    char* ws = (char*)d_ws;
    unsigned long long* scratch = (unsigned long long*)ws; ws += (size_t)NB * KK * 256 * 8;
    int*   idxA   = (int*)ws;      ws += (size_t)NB * KK * 4;
    int*   minN   = (int*)ws;      ws += (size_t)NB * KK * 4;
    float* normA  = (float*)ws;    ws += (size_t)NB * KK * 4;
    float* resp   = (float*)ws;    ws += (size_t)NB * NF * 4;
    float* normB  = (float*)ws;    ws += (size_t)NB * NF * 4;
    ushort_t* desc_h = (ushort_t*)ws; ws += (size_t)NB * KK * COUT * 2;
    ushort_t* desc_l = (ushort_t*)ws; ws += (size_t)NB * KK * COUT * 2;
    ushort_t* Wh  = (ushort_t*)ws; ws += (size_t)COUT * 32 * 2;
    ushort_t* Wl  = (ushort_t*)ws; ws += (size_t)COUT * 32 * 2;
    unsigned* fBhl = (unsigned*)ws; ws += (size_t)NB * COUT * NF * 4;

    prep_kernel  <<<1, 256, 0, stream>>>(Wc, Wh, Wl);
    conv_kernel  <<<2048, 256, 0, stream>>>(xA, xB, Wh, Wl, bc, fBhl, resp, normB);
    select_kernel<<<NB * KK, 256, 0, stream>>>(resp, xA, Wc, bc, idxA, desc_h, desc_l, normA);
    knn_kernel   <<<dim3(256, NB), 256, 0, stream>>>(fBhl, desc_h, desc_l, normA, normB, scratch);
    reduce_kernel<<<NB * KK, 64, 0, stream>>>(scratch, minN);
    mlp_kernel   <<<8, 128, 0, stream>>>(idxA, minN,
                                         W1r, b1r, W2r, b2r,
                                         W1c, b1c, W2c, b2c, out);
}